// Round 1
// baseline (476.697 us; speedup 1.0000x reference)
//
#include <hip/hip_runtime.h>

typedef unsigned short u16;
typedef __bf16 bfx8 __attribute__((ext_vector_type(8)));
typedef float f32x4 __attribute__((ext_vector_type(4)));

#define B_ 2
#define S_ 2048
#define D_ 2048
#define H_ 16
#define HD_ 128
#define SD_ 6144   // 3*D row stride of qkv

__device__ __forceinline__ u16 f2bf(float f) {
  union { float f; unsigned u; } v; v.f = f;
  unsigned r = v.u + 0x7fffu + ((v.u >> 16) & 1u);
  return (u16)(r >> 16);
}
__device__ __forceinline__ float bf2f(u16 b) {
  union { unsigned u; float f; } v; v.u = ((unsigned)b) << 16;
  return v.f;
}
__device__ __forceinline__ void gload_lds16(const void* g, void* l) {
  __builtin_amdgcn_global_load_lds((const __attribute__((address_space(1))) void*)g,
                                   (__attribute__((address_space(3))) void*)l, 16, 0, 0);
}

// ---------------- fp32 -> bf16 elementwise (vectorized) ----------------
__global__ __launch_bounds__(256) void cvt_kernel(const float* __restrict__ in,
                                                  u16* __restrict__ out, int n4) {
  int i = blockIdx.x * blockDim.x + threadIdx.x;
  int stride = gridDim.x * blockDim.x;
  for (int idx = i; idx < n4; idx += stride) {
    float4 v = ((const float4*)in)[idx];
    uint2 o;
    o.x = (unsigned)f2bf(v.x) | ((unsigned)f2bf(v.y) << 16);
    o.y = (unsigned)f2bf(v.z) | ((unsigned)f2bf(v.w) << 16);
    ((uint2*)out)[idx] = o;
  }
}

// ---------------- fp32 [R][C] -> bf16 [C][R] transpose-convert ----------------
__global__ __launch_bounds__(256) void transpose_cvt(const float* __restrict__ in,
                                                     u16* __restrict__ out,
                                                     int R, int C) {
  __shared__ float tile[32][33];
  int tx = threadIdx.x, ty = threadIdx.y;
  int c0 = blockIdx.x * 32, r0 = blockIdx.y * 32;
  for (int i = 0; i < 4; ++i)
    tile[ty + i * 8][tx] = in[(size_t)(r0 + ty + i * 8) * C + c0 + tx];
  __syncthreads();
  for (int i = 0; i < 4; ++i)
    out[(size_t)(c0 + ty + i * 8) * R + r0 + tx] = f2bf(tile[tx][ty + i * 8]);
}

// ---------------- V transpose: qkv[b,s,2D+h*HD+hd] -> vt[bh][hd][s] ----------------
__global__ __launch_bounds__(256) void transpose_v(const u16* __restrict__ qkv,
                                                   u16* __restrict__ vt) {
  __shared__ u16 tile[32][33];
  int tx = threadIdx.x, ty = threadIdx.y;
  int bh = blockIdx.z;
  int b = bh >> 4, h = bh & 15;
  int s0 = blockIdx.x * 32, d0 = blockIdx.y * 32;
  const u16* src = qkv + (size_t)b * S_ * SD_ + 2 * D_ + h * HD_;
  for (int i = 0; i < 4; ++i)
    tile[ty + i * 8][tx] = src[(size_t)(s0 + ty + i * 8) * SD_ + d0 + tx];
  __syncthreads();
  u16* dst = vt + (size_t)bh * HD_ * S_;
  for (int i = 0; i < 4; ++i)
    dst[(size_t)(d0 + ty + i * 8) * S_ + s0 + tx] = tile[tx][ty + i * 8];
}

// ---------------- bf16 GEMM: C[M][N] = A[M][K] * Bt[N][K]^T + bias ----------------
// 128x128 tile, BK=64, 4 waves (2x2), each wave 64x64 = 4x4 frags of 16x16x32.
template<int OUT_BF16>
__global__ __launch_bounds__(256) void gemm_bt(const u16* __restrict__ A,
                                               const u16* __restrict__ Bt,
                                               const float* __restrict__ bias,
                                               void* __restrict__ Cout,
                                               int M, int N, int K) {
  __shared__ u16 ldsA[128 * 64];
  __shared__ u16 ldsB[128 * 64];
  int t = threadIdx.x, l = t & 63, w = t >> 6;
  int lr = l & 15, lg = l >> 4;
  int wr = w >> 1, wc = w & 1;
  int m0 = blockIdx.y * 128, n0 = blockIdx.x * 128;

  f32x4 acc[4][4];
  for (int i = 0; i < 4; ++i)
    for (int j = 0; j < 4; ++j)
      for (int r = 0; r < 4; ++r) acc[i][j][r] = 0.0f;

  int rA = t >> 3;            // 0..31 row within 32-row group
  int cA = (t & 7) * 8;       // col offset (elems)

  for (int k0 = 0; k0 < K; k0 += 64) {
    for (int i = 0; i < 4; ++i)
      gload_lds16(A + (size_t)(m0 + i * 32 + rA) * K + k0 + cA, &ldsA[i * 2048 + t * 8]);
    for (int i = 0; i < 4; ++i)
      gload_lds16(Bt + (size_t)(n0 + i * 32 + rA) * K + k0 + cA, &ldsB[i * 2048 + t * 8]);
    __syncthreads();
    for (int kk = 0; kk < 2; ++kk) {
      bfx8 af[4], bfr[4];
      for (int i = 0; i < 4; ++i)
        af[i] = *(const bfx8*)&ldsA[(wr * 64 + i * 16 + lr) * 64 + kk * 32 + lg * 8];
      for (int j = 0; j < 4; ++j)
        bfr[j] = *(const bfx8*)&ldsB[(wc * 64 + j * 16 + lr) * 64 + kk * 32 + lg * 8];
      for (int i = 0; i < 4; ++i)
        for (int j = 0; j < 4; ++j)
          acc[i][j] = __builtin_amdgcn_mfma_f32_16x16x32_bf16(af[i], bfr[j], acc[i][j], 0, 0, 0);
    }
    __syncthreads();
  }

  for (int i = 0; i < 4; ++i) {
    int row = m0 + wr * 64 + i * 16 + lg * 4;
    for (int j = 0; j < 4; ++j) {
      int col = n0 + wc * 64 + j * 16 + lr;
      float bz = bias[col];
      for (int r = 0; r < 4; ++r) {
        float v = acc[i][j][r] + bz;
        if (OUT_BF16)
          ((u16*)Cout)[(size_t)(row + r) * N + col] = f2bf(v);
        else
          ((float*)Cout)[(size_t)(row + r) * N + col] = v;
      }
    }
  }
}

// ---------------- causal flash attention ----------------
// grid: (S/128, B*H), 256 threads. Wave w handles q rows [q0+w*32, +32).
__global__ __launch_bounds__(256) void attn_kernel(const u16* __restrict__ qkv,
                                                   const u16* __restrict__ vt,
                                                   u16* __restrict__ ctx) {
  __shared__ u16 Klds[64 * 128];   // [key][hd]
  __shared__ u16 Vlds[128 * 64];   // [hd][key]  (from vt)
  __shared__ u16 Plds[4][32 * 64]; // per-wave P [q][key]

  int t = threadIdx.x, l = t & 63, w = t >> 6;
  int lr = l & 15, lg = l >> 4;
  int bh = blockIdx.y, b = bh >> 4, h = bh & 15;
  int q0 = blockIdx.x * 128;
  const float scale = 0.08838834764831845f;  // 1/sqrt(128)

  // load Q fragments, pre-scaled, as bf16
  bfx8 qf[2][4];
  {
    const u16* qbase = qkv + (size_t)(b * S_ + q0 + w * 32) * SD_ + h * HD_;
    for (int m = 0; m < 2; ++m)
      for (int kk = 0; kk < 4; ++kk) {
        const u16* src = qbase + (size_t)(m * 16 + lr) * SD_ + kk * 32 + lg * 8;
        union { uint4 u; u16 s[8]; bfx8 bv; } iv, ov;
        iv.u = *(const uint4*)src;
        for (int j = 0; j < 8; ++j) ov.s[j] = f2bf(bf2f(iv.s[j]) * scale);
        qf[m][kk] = ov.bv;
      }
  }

  f32x4 o[2][8];
  float mrun[2][4], lrun[2][4];
  for (int m = 0; m < 2; ++m) {
    for (int ht = 0; ht < 8; ++ht)
      for (int r = 0; r < 4; ++r) o[m][ht][r] = 0.0f;
    for (int r = 0; r < 4; ++r) { mrun[m][r] = -INFINITY; lrun[m][r] = 0.0f; }
  }

  int nt = (q0 + 128) >> 6;  // causal: only tiles touching <= q0+127
  const u16* kbase = qkv + (size_t)b * S_ * SD_ + D_ + h * HD_;
  const u16* vbase = vt + (size_t)bh * HD_ * S_;

  for (int kt = 0; kt < nt; ++kt) {
    // stage K tile [64][128] and Vt tile [128][64]
    for (int i = 0; i < 4; ++i)
      gload_lds16(kbase + (size_t)(kt * 64 + i * 16 + (t >> 4)) * SD_ + (t & 15) * 8,
                  &Klds[i * 2048 + t * 8]);
    for (int i = 0; i < 4; ++i)
      gload_lds16(vbase + (size_t)(i * 32 + (t >> 3)) * S_ + kt * 64 + (t & 7) * 8,
                  &Vlds[i * 2048 + t * 8]);
    __syncthreads();

    // S = Q K^T  (D layout: row = q = lg*4+r, col = key = lr)
    f32x4 sacc[2][4];
    for (int m = 0; m < 2; ++m)
      for (int n = 0; n < 4; ++n)
        for (int r = 0; r < 4; ++r) sacc[m][n][r] = 0.0f;
    for (int n = 0; n < 4; ++n) {
      bfx8 kf[4];
      for (int kk = 0; kk < 4; ++kk)
        kf[kk] = *(const bfx8*)&Klds[(n * 16 + lr) * 128 + kk * 32 + lg * 8];
      for (int m = 0; m < 2; ++m)
        for (int kk = 0; kk < 4; ++kk)
          sacc[m][n] = __builtin_amdgcn_mfma_f32_16x16x32_bf16(qf[m][kk], kf[kk], sacc[m][n], 0, 0, 0);
    }

    // online softmax + P -> LDS (bf16)
    for (int m = 0; m < 2; ++m) {
      for (int r = 0; r < 4; ++r) {
        int qa = q0 + w * 32 + m * 16 + lg * 4 + r;
        float s[4];
        float tmax = -INFINITY;
        for (int n = 0; n < 4; ++n) {
          int key = kt * 64 + n * 16 + lr;
          s[n] = (key > qa) ? -INFINITY : sacc[m][n][r];
          tmax = fmaxf(tmax, s[n]);
        }
        for (int d = 1; d < 16; d <<= 1) tmax = fmaxf(tmax, __shfl_xor(tmax, d, 64));
        float mnew = fmaxf(mrun[m][r], tmax);
        float corr = __expf(mrun[m][r] - mnew);
        float psum = 0.0f;
        u16 pb[4];
        for (int n = 0; n < 4; ++n) {
          float p = __expf(s[n] - mnew);
          psum += p;
          pb[n] = f2bf(p);
        }
        for (int d = 1; d < 16; d <<= 1) psum += __shfl_xor(psum, d, 64);
        lrun[m][r] = lrun[m][r] * corr + psum;
        mrun[m][r] = mnew;
        for (int ht = 0; ht < 8; ++ht) o[m][ht][r] *= corr;
        for (int n = 0; n < 4; ++n)
          Plds[w][(m * 16 + lg * 4 + r) * 64 + n * 16 + lr] = pb[n];
      }
    }

    // O += P V   (A = P [q][key], B = Vt_lds [hd][key] -> B[k=key][n=hd])
    for (int m = 0; m < 2; ++m)
      for (int kk = 0; kk < 2; ++kk) {
        bfx8 pa = *(const bfx8*)&Plds[w][(m * 16 + lr) * 64 + kk * 32 + lg * 8];
        for (int ht = 0; ht < 8; ++ht) {
          bfx8 vb = *(const bfx8*)&Vlds[(ht * 16 + lr) * 64 + kk * 32 + lg * 8];
          o[m][ht] = __builtin_amdgcn_mfma_f32_16x16x32_bf16(pa, vb, o[m][ht], 0, 0, 0);
        }
      }
    __syncthreads();
  }

  // epilogue: ctx[b, qa, h*HD + hd] = o / l
  for (int m = 0; m < 2; ++m)
    for (int r = 0; r < 4; ++r) {
      float inv = 1.0f / lrun[m][r];
      int qa = q0 + w * 32 + m * 16 + lg * 4 + r;
      u16* dst = ctx + (size_t)(b * S_ + qa) * D_ + h * HD_;
      for (int ht = 0; ht < 8; ++ht)
        dst[ht * 16 + lr] = f2bf(o[m][ht][r] * inv);
    }
}

extern "C" void kernel_launch(void* const* d_in, const int* in_sizes, int n_in,
                              void* d_out, int out_size, void* d_ws, size_t ws_size,
                              hipStream_t stream) {
  const float* hs     = (const float*)d_in[0];
  const float* w_attn = (const float*)d_in[1];
  const float* b_attn = (const float*)d_in[2];
  const float* w_proj = (const float*)d_in[3];
  const float* b_proj = (const float*)d_in[4];

  // workspace layout (u16 elems): total 64Mi elems = 128 MiB
  u16* Xb     = (u16*)d_ws;            // [4096][2048]        8,388,608
  u16* Wqkvt  = Xb     + 8388608;      // [6144][2048]       12,582,912
  u16* Wprojt = Wqkvt  + 12582912;     // [2048][2048]        4,194,304
  u16* qkvb   = Wprojt + 4194304;      // [4096][6144]       25,165,824
  u16* Vt     = qkvb   + 25165824;     // [32][128][2048]     8,388,608
  u16* ctxb   = Vt     + 8388608;      // [4096][2048]        8,388,608

  cvt_kernel<<<2048, 256, 0, stream>>>(hs, Xb, (B_ * S_ * D_) / 4);
  transpose_cvt<<<dim3(192, 64), dim3(32, 8), 0, stream>>>(w_attn, Wqkvt, D_, 3 * D_);
  transpose_cvt<<<dim3(64, 64), dim3(32, 8), 0, stream>>>(w_proj, Wprojt, D_, D_);
  gemm_bt<1><<<dim3(48, 32), 256, 0, stream>>>(Xb, Wqkvt, b_attn, qkvb, 4096, 6144, 2048);
  transpose_v<<<dim3(64, 4, 32), dim3(32, 8), 0, stream>>>(qkvb, Vt);
  attn_kernel<<<dim3(16, 32), 256, 0, stream>>>(qkvb, Vt, ctxb);
  gemm_bt<0><<<dim3(16, 32), 256, 0, stream>>>(ctxb, Wprojt, b_proj, d_out, 4096, 2048, 2048);
}